// Round 6
// baseline (446.146 us; speedup 1.0000x reference)
//
#include <hip/hip_runtime.h>

// Correlation1D on MI355X (gfx950), round 10 (R9 + race fix).
// out[b,d,h,w] = (1/256) * sum_c in1[b,c,h,w] * in2[b,c,h,w+d-40]
// B=8 C=256 H=96 W=192 D=81 PAD=40.
//
// R10: producer-consumer wave specialization (R9) with the G12 atomic bug
// fixed: __hip_atomic_fetch_add runs PER-LANE (coalesced to +64/wave, m20),
// so R9's counters released consumers after ONE producer wave signaled ->
// uninit-LDS reads (absmax 2e21). Fix: lane-0-only signals (one bump per
// wave; wave-wide lgkmcnt(0) before the signal preserves release order).
// Structure: 512-thread blocks; waves 0-3 consumers (R8 compute/band/
// epilogue), waves 4-7 producers streaming global->reg->LDS, 2-chunk reg
// prefetch, counted vmcnt, NO main-loop barriers (LDS flag counters +
// s_sleep poll). 24 waves/CU, continuous load-issue duty cycle.

typedef __attribute__((ext_vector_type(8))) short short8;     // 8 bf16
typedef __attribute__((ext_vector_type(4))) short short4v;    // 4 bf16
typedef __attribute__((ext_vector_type(4))) float float4v;

#if defined(__has_builtin)
#if __has_builtin(__builtin_amdgcn_mfma_f32_16x16x16bf16_1k)
#define HAVE_MFMA16 1
#endif
#endif
#ifndef HAVE_MFMA16
#define HAVE_MFMA16 0
#endif

__device__ __forceinline__ unsigned short f2bf(float f) {
  // round-to-nearest-even fp32 -> bf16
  unsigned int u = __float_as_uint(f);
  return (unsigned short)((u + 0x7FFFu + ((u >> 16) & 1u)) >> 16);
}

__global__ __launch_bounds__(512, 6) void corr1d_kernel(
    const float* __restrict__ in1, const float* __restrict__ in2,
    float* __restrict__ out) {
  constexpr int W = 192, H = 96, C = 256, D = 81;
  constexpr int HW = H * W;          // c-stride in elements
  constexpr int KC = 16;             // channels per chunk (16 chunks)
  constexpr int SR = 196;            // LDS row stride: 784 B (16B-aligned)
  constexpr int ES = 196;            // epilogue row stride
  constexpr int BUF = KC * SR;       // floats per array per buffer (3136)

  // LDS: 2 ping-pong buffers x (A[16][196] + B[16][196]) = 50,176 B + flags
  // -> 3 blocks/CU (150.6 KB). Epilogue overlays E[41][196].
  __shared__ __align__(16) float smem[4 * BUF];
  __shared__ int fullCnt[2];         // producer fill signals: +1 per WAVE
  __shared__ int freeCnt[2];         // consumer free signals: +1 per WAVE
  float* E = smem;

  const int bh = blockIdx.x;
  const int b = bh / H, h = bh % H;
  const int tid = threadIdx.x;
  const int lane = tid & 63;
  const int wid = tid >> 6;          // 0..3 consumers, 4..7 producers
  const int l15 = lane & 15, lq = lane >> 4;
  const int base = (b * C * H + h) * W;

  if (tid < 2) { fullCnt[tid] = 0; freeCnt[tid] = 0; }
  __syncthreads();

  float4v acc[3][6];  // defined on consumer path only

  if (wid >= 4) {
    // ================= PRODUCER wave pv (rows 4pv..4pv+3 of A and B) ======
    const int pv = wid - 4;
    int soff[3], loff[3];
#pragma unroll
    for (int g = 0; g < 3; ++g) {
      const int fidx = 256 * g + 4 * lane;   // 0..1020
      const int r = fidx / 192;
      const int col = fidx - 192 * r;
      soff[g] = (4 * pv + r) * HW + col;
      loff[g] = (4 * pv + r) * SR + col;
    }
    const float* in1p = in1 + base;
    const float* in2p = in2 + base;

    float4v rA0[3], rB0[3], rA1[3], rB1[3];
    auto LOAD0 = [&](int m) {
      const float* g1 = in1p + KC * m * HW;
      const float* g2 = in2p + KC * m * HW;
#pragma unroll
      for (int g = 0; g < 3; ++g) {
        rA0[g] = *(const float4v*)(g1 + soff[g]);
        rB0[g] = *(const float4v*)(g2 + soff[g]);
      }
    };
    auto LOAD1 = [&](int m) {
      const float* g1 = in1p + KC * m * HW;
      const float* g2 = in2p + KC * m * HW;
#pragma unroll
      for (int g = 0; g < 3; ++g) {
        rA1[g] = *(const float4v*)(g1 + soff[g]);
        rB1[g] = *(const float4v*)(g2 + soff[g]);
      }
    };
    auto WRITE0 = [&]() {            // even chunks -> buffer 0
      float* As = smem;
      float* Bs = smem + BUF;
#pragma unroll
      for (int g = 0; g < 3; ++g) {
        *(float4v*)(As + loff[g]) = rA0[g];
        *(float4v*)(Bs + loff[g]) = rB0[g];
      }
    };
    auto WRITE1 = [&]() {            // odd chunks -> buffer 1
      float* As = smem + 2 * BUF;
      float* Bs = smem + 3 * BUF;
#pragma unroll
      for (int g = 0; g < 3; ++g) {
        *(float4v*)(As + loff[g]) = rA1[g];
        *(float4v*)(Bs + loff[g]) = rB1[g];
      }
    };
    auto waitFree = [&](int m) {     // chunk m may overwrite buffer m&1 once
      const int need = 4 * (m >> 1); // chunk m-2 fully consumed (4 consumers)
      if (need > 0) {
        while (__hip_atomic_load(&freeCnt[m & 1], __ATOMIC_ACQUIRE,
                                 __HIP_MEMORY_SCOPE_WORKGROUP) < need)
          __builtin_amdgcn_s_sleep(1);
      }
      __builtin_amdgcn_sched_barrier(0);   // no ds_write hoists above poll
    };
    auto signalFull = [&](int p) {
      asm volatile("s_waitcnt lgkmcnt(0)" ::: "memory");  // ds_writes landed
      if (lane == 0)                       // ONE bump per wave (G12 fix)
        __hip_atomic_fetch_add(&fullCnt[p], 1, __ATOMIC_RELEASE,
                               __HIP_MEMORY_SCOPE_WORKGROUP);
    };

    LOAD0(0);
    LOAD1(1);                                      // 12 loads outstanding
#pragma unroll 1
    for (int t = 0; t < 7; ++t) {                  // chunks 0..13
      const int m = 2 * t;
      asm volatile("s_waitcnt vmcnt(6)" ::: "memory");  // set m arrived
      waitFree(m);
      WRITE0(); signalFull(0);
      LOAD0(m + 2);                                // back to 12 outstanding
      asm volatile("s_waitcnt vmcnt(6)" ::: "memory");  // set m+1 arrived
      waitFree(m + 1);
      WRITE1(); signalFull(1);
      if (m + 3 < 16) LOAD1(m + 3);
    }
    asm volatile("s_waitcnt vmcnt(6)" ::: "memory");    // chunk 14 (15 live)
    waitFree(14); WRITE0(); signalFull(0);
    asm volatile("s_waitcnt vmcnt(0)" ::: "memory");    // chunk 15: drain
    waitFree(15); WRITE1(); signalFull(1);
  } else {
    // ================= CONSUMER wave wv (w-tiles 3wv..3wv+2) ==============
    const int wv = wid;
#pragma unroll
    for (int i = 0; i < 3; ++i)
#pragma unroll
      for (int jj = 0; jj < 6; ++jj) acc[i][jj] = (float4v){0.f, 0.f, 0.f, 0.f};

    auto compute_chunk = [&](int p) {
      const float* As = smem + p * (2 * BUF);
      const float* Bs = As + BUF;
#if HAVE_MFMA16
      short4v af[3];
#pragma unroll
      for (int i = 0; i < 3; ++i) {
        const float* ap = As + 48 * wv + 16 * i + l15;
        unsigned short o[4];
#pragma unroll
        for (int t = 0; t < 4; ++t) o[t] = f2bf(ap[(4 * lq + t) * SR]);
        af[i] = *(const short4v*)o;
      }
#pragma unroll
      for (int jt = 0; jt < 8; ++jt) {
        const int j = 16 * (3 * wv + jt) + l15;     // padded j coord
        const bool ok = (j >= 40) && (j < 232);     // in2 col = j-40
        const float* bp = Bs + (ok ? (j - 40) : 0);
        unsigned short o[4];
#pragma unroll
        for (int t = 0; t < 4; ++t) {
          float v = ok ? bp[(4 * lq + t) * SR] : 0.0f;
          o[t] = f2bf(v);
        }
        short4v bfr = *(const short4v*)o;
#pragma unroll
        for (int i = 0; i < 3; ++i) {
          const int jj = jt - i;                    // compile-time
          if (jj >= 0 && jj < 6)
            acc[i][jj] = __builtin_amdgcn_mfma_f32_16x16x16bf16_1k(
                af[i], bfr, acc[i][jj], 0, 0, 0);
        }
      }
#else
      const bool okq = (lq < 2);
      const int rb = okq ? 8 * lq : 0;
      short8 af[3];
#pragma unroll
      for (int i = 0; i < 3; ++i) {
        const float* ap = As + 48 * wv + 16 * i + l15;
        unsigned short o[8];
#pragma unroll
        for (int t = 0; t < 8; ++t) {
          float v = ap[(rb + t) * SR];
          o[t] = okq ? f2bf(v) : (unsigned short)0;
        }
        af[i] = *(const short8*)o;
      }
#pragma unroll
      for (int jt = 0; jt < 8; ++jt) {
        const int j = 16 * (3 * wv + jt) + l15;
        const bool ok = (j >= 40) && (j < 232);
        const float* bp = Bs + (ok ? (j - 40) : 0);
        unsigned short o[8];
#pragma unroll
        for (int t = 0; t < 8; ++t) {
          float v = bp[(rb + t) * SR];
          o[t] = (ok && okq) ? f2bf(v) : (unsigned short)0;
        }
        short8 bfr = *(const short8*)o;
#pragma unroll
        for (int i = 0; i < 3; ++i) {
          const int jj = jt - i;
          if (jj >= 0 && jj < 6)
            acc[i][jj] = __builtin_amdgcn_mfma_f32_16x16x32_bf16(
                af[i], bfr, acc[i][jj], 0, 0, 0);
        }
      }
#endif
    };
    auto waitFull = [&](int m) {     // fill m/2+1 of buffer m&1 complete
      const int need = 4 * (m >> 1) + 4;
      while (__hip_atomic_load(&fullCnt[m & 1], __ATOMIC_ACQUIRE,
                               __HIP_MEMORY_SCOPE_WORKGROUP) < need)
        __builtin_amdgcn_s_sleep(1);
      __builtin_amdgcn_sched_barrier(0);   // no ds_read hoists above poll
    };
    auto signalFree = [&](int p) {
      asm volatile("s_waitcnt lgkmcnt(0)" ::: "memory");  // my reads done
      if (lane == 0)                       // ONE bump per wave (G12 fix)
        __hip_atomic_fetch_add(&freeCnt[p], 1, __ATOMIC_RELEASE,
                               __HIP_MEMORY_SCOPE_WORKGROUP);
    };

#pragma unroll 1
    for (int t = 0; t < 8; ++t) {                  // chunks 2t, 2t+1
      waitFull(2 * t);
      compute_chunk(0);
      signalFree(0);
      waitFull(2 * t + 1);
      compute_chunk(1);
      signalFree(1);
    }
  }

  // ---- epilogue: D layout col(j)=l15, row(w)=4lq+r -> d = 16jj+l15-4lq-r.
  // Two d-phases through LDS overlay; all 512 threads store (coalesced
  // float4). Producer waves skip the acc->E write (their acc is undef).
  const float scale = 1.0f / 256.0f;
#pragma unroll
  for (int p = 0; p < 2; ++p) {
    const int dlo = p ? 41 : 0;
    const int nd  = p ? 40 : 41;
    __syncthreads();                 // buffers / previous E free
    if (wid < 4) {
      const int wv = wid;
#pragma unroll
      for (int i = 0; i < 3; ++i)
#pragma unroll
        for (int jj = 0; jj < 6; ++jj)
#pragma unroll
          for (int r = 0; r < 4; ++r) {
            const int d = 16 * jj + l15 - 4 * lq - r;
            const int w = 48 * wv + 16 * i + 4 * lq + r;
            if (d >= dlo && d < dlo + nd)
              E[(d - dlo) * ES + w] = acc[i][jj][r] * scale;
          }
    }
    __syncthreads();
    for (int t = tid; t < nd * 48; t += 512) {
      const int dr = t / 48, g = t % 48;
      float4v val = *(const float4v*)(E + dr * ES + 4 * g);
      *(float4v*)(out + ((b * D + dlo + dr) * H + h) * W + 4 * g) = val;
    }
  }
}

extern "C" void kernel_launch(void* const* d_in, const int* in_sizes, int n_in,
                              void* d_out, int out_size, void* d_ws, size_t ws_size,
                              hipStream_t stream) {
  const float* in1 = (const float*)d_in[0];
  const float* in2 = (const float*)d_in[1];
  float* out = (float*)d_out;
  (void)in_sizes; (void)n_in; (void)out_size; (void)d_ws; (void)ws_size;
  corr1d_kernel<<<dim3(768), dim3(512), 0, stream>>>(in1, in2, out);
}